// Round 9
// baseline (340.728 us; speedup 1.0000x reference)
//
#include <hip/hip_runtime.h>
#include <hip/hip_bf16.h>
#include <stdint.h>
#include <stddef.h>

using bf16 = __hip_bfloat16;

typedef __attribute__((ext_vector_type(4))) float f32x4;
typedef __attribute__((ext_vector_type(8))) short bf16x8;
typedef __attribute__((ext_vector_type(4))) unsigned short u16x4;

#define K_DIM 4096
#define M_ROWS 8192
#define BM 256
#define BN 128
#define BK 32
#define NTT (K_DIM / BK)     // 128 K-tiles
#define MT2 (M_ROWS / BM)    // 32
#define NT2 (K_DIM / BN)     // 32

// ---------------------------------------------------------------------------
// Kernel 1: f32 -> bf16 conversion (vectorized, grid-stride)
// ---------------------------------------------------------------------------
__global__ void conv_bf16(const float* __restrict__ in, bf16* __restrict__ outb, int n4) {
  int idx = blockIdx.x * blockDim.x + threadIdx.x;
  int stride = gridDim.x * blockDim.x;
  for (int k = idx; k < n4; k += stride) {
    f32x4 v = ((const f32x4*)in)[k];
    bf16 tmp[4];
    tmp[0] = __float2bfloat16(v.x);
    tmp[1] = __float2bfloat16(v.y);
    tmp[2] = __float2bfloat16(v.z);
    tmp[3] = __float2bfloat16(v.w);
    ((u16x4*)outb)[k] = *(const u16x4*)tmp;
  }
}

// ---------------------------------------------------------------------------
// Kernel 2: build G^T in bf16 (verified round 1).
// ---------------------------------------------------------------------------
__global__ void build_gt(const float* __restrict__ core0, const float* __restrict__ core1,
                         bf16* __restrict__ GT) {
  int j = blockIdx.x >> 6;
  int i = blockIdx.x & 63;
  __shared__ float c0s[64][16];
  __shared__ float c1s[64][16];
  int t = threadIdx.x;
#pragma unroll
  for (int rep = 0; rep < 4; ++rep) {
    int idx = rep * 256 + t;
    int row = idx >> 4;
    int b = idx & 15;
    size_t base = ((size_t)(j * 64 + row) * 64 + i) * 16 + b;
    c1s[row][b] = core1[base];
    c0s[row][b] = core0[base];
  }
  __syncthreads();
  int x = t & 63;
  int ys = t >> 6;
  float r1[16];
#pragma unroll
  for (int b = 0; b < 16; ++b) r1[b] = c1s[x][b];
#pragma unroll
  for (int yy = 0; yy < 16; ++yy) {
    int y = ys * 16 + yy;
    float acc = 0.f;
#pragma unroll
    for (int b = 0; b < 16; ++b) acc += r1[b] * c0s[y][b];
    GT[((size_t)(y * 64 + i) << 12) + (size_t)(j * 64 + x)] = __float2bfloat16(acc);
  }
}

// ---------------------------------------------------------------------------
// Kernel 3: 256x128 tile / BK=32 / 4 waves / 48 KiB LDS => TWO independent
// blocks per CU. Cross-block TLP provides the LDS<->MFMA overlap that the
// single-block lockstep schedules (R3-R8, all ~270us) structurally cannot.
// Superrow LDS layout: tile [R][32] stored as [R/2][64]; element (r,k) at
// [r>>1][((r&1)*4 + k/8) ^ ((r>>1)&7)]*8 + k%8 -- conflict-free 8-slot XOR,
// linear gload_lds destinations (src pre-swizzled).
// ---------------------------------------------------------------------------
__device__ __forceinline__ void gload_lds16(const bf16* g, bf16* l) {
  __builtin_amdgcn_global_load_lds(
      (const __attribute__((address_space(1))) unsigned int*)(g),
      (__attribute__((address_space(3))) unsigned int*)(l),
      16, 0, 0);
}

#define BARRIER() __builtin_amdgcn_s_barrier()
#define SP1() __builtin_amdgcn_s_setprio(1)
#define SP0() __builtin_amdgcn_s_setprio(0)
#define VMCNT0() asm volatile("s_waitcnt vmcnt(0)" ::: "memory")

__global__ __launch_bounds__(256, 2)
void gemm_xg(const bf16* __restrict__ Xb, const bf16* __restrict__ GT,
             const float* __restrict__ bias, float* __restrict__ out) {
  // A: 256 rows -> 128 superrows x 64 elems (16 KiB); B: 128 rows -> 64 x 64 (8 KiB)
  __shared__ bf16 As[2][128 * 64];
  __shared__ bf16 Bs[2][64 * 64];

  // XCD-aware swizzle: nwg = 1024, divisible by 8
  int bid = blockIdx.x;
  int sb = (bid & 7) * (MT2 * NT2 / 8) + (bid >> 3);
  int bm = sb >> 5;          // 0..31
  int bn = sb & 31;          // 0..31

  int t = threadIdx.x;
  int lane = t & 63;
  int wid = t >> 6;          // 4 waves

  // ---- staging addressing ----
  int ssr = t >> 3;                       // 0..31 superrow within a call
  int sslot = t & 7;                      // dest 16B slot (linear)
  int sp = sslot ^ (ssr & 7);             // source slot (inverse swizzle)
  int srowpar = sp >> 2;                  // source row parity
  int skofs = (sp & 3) * 8;               // source k offset
  const bf16* gA0 = Xb + ((size_t)(bm * BM + 2 * ssr + srowpar) * K_DIM) + skofs;
  const bf16* gB0 = GT + ((size_t)(bn * BN + 2 * ssr + srowpar) * K_DIM) + skofs;
  int ldst = ssr * 64 + sslot * 8;        // dest elem offset (linear 16B/thread)

  auto stage = [&](int buf, int kt) {
    // A: 4 calls (128 superrows), B: 2 calls (64 superrows)
#pragma unroll
    for (int h = 0; h < 4; ++h)
      gload_lds16(gA0 + (size_t)(h * 64) * K_DIM + kt * BK,
                  &As[buf][h * 32 * 64 + ldst]);
#pragma unroll
    for (int h = 0; h < 2; ++h)
      gload_lds16(gB0 + (size_t)(h * 64) * K_DIM + kt * BK,
                  &Bs[buf][h * 32 * 64 + ldst]);
  };

  // ---- fragment addressing ----
  int wm = wid >> 1;         // 0..1 (M half)
  int wn = wid & 1;          // 0..1 (N half)
  int lr = lane & 15;
  int g4 = lane >> 4;        // k-slot 0..3
  int lh = lr >> 1;
  int lp = lr & 1;
  int aslot = ((lp << 2) | g4) ^ lh;      // sr&7 == lh for all frags
  int aoff = (wm * 64 + lh) * 64 + aslot * 8;   // + mi*512
  int boff = (wn * 32 + lh) * 64 + aslot * 8;   // + ni*512

  f32x4 acc[8][4] = {};

  auto compute = [&](const bf16* Ac, const bf16* Bc) {
    bf16x8 af[8], bf4[4];
#pragma unroll
    for (int mi = 0; mi < 8; ++mi)
      af[mi] = *(const bf16x8*)&Ac[aoff + mi * 512];
#pragma unroll
    for (int ni = 0; ni < 4; ++ni)
      bf4[ni] = *(const bf16x8*)&Bc[boff + ni * 512];
    SP1();
#pragma unroll
    for (int mi = 0; mi < 8; ++mi)
#pragma unroll
      for (int ni = 0; ni < 4; ++ni)
        acc[mi][ni] = __builtin_amdgcn_mfma_f32_16x16x32_bf16(
            af[mi], bf4[ni], acc[mi][ni], 0, 0, 0);
    SP0();
  };

  // ---- prologue ----
  stage(0, 0);
  VMCNT0();
  BARRIER();

  // ---- main loop: 64 pairs of K-tiles ----
#pragma unroll 1
  for (int i = 0; i < NTT / 2; ++i) {
    // tile 2i: read buf0, stage 2i+1 -> buf1
    stage(1, 2 * i + 1);
    compute(&As[0][0], &Bs[0][0]);
    VMCNT0();
    BARRIER();
    // tile 2i+1: read buf1, stage 2i+2 -> buf0
    if (i + 1 < NTT / 2) stage(0, 2 * i + 2);
    compute(&As[1][0], &Bs[1][0]);
    VMCNT0();
    BARRIER();
  }

  // ---- epilogue: C/D layout col = lane&15, row = (lane>>4)*4 + r ----
  int colbase = bn * BN + wn * 64 + lr;
  int rowbase = bm * BM + wm * 128 + g4 * 4;
#pragma unroll
  for (int ni = 0; ni < 4; ++ni) {
    int col = colbase + ni * 16;
    float bv = bias[col];
#pragma unroll
    for (int mi = 0; mi < 8; ++mi) {
#pragma unroll
      for (int r = 0; r < 4; ++r) {
        int row = rowbase + mi * 16 + r;
        out[(size_t)row * K_DIM + col] = acc[mi][ni][r] + bv;
      }
    }
  }
}

// ---------------------------------------------------------------------------
extern "C" void kernel_launch(void* const* d_in, const int* in_sizes, int n_in,
                              void* d_out, int out_size, void* d_ws, size_t ws_size,
                              hipStream_t stream) {
  const float* x     = (const float*)d_in[0];
  const float* core0 = (const float*)d_in[1];
  const float* core1 = (const float*)d_in[2];
  const float* bias  = (const float*)d_in[3];
  float* out = (float*)d_out;

  bf16* Xb = (bf16*)d_ws;
  bf16* GT = (bf16*)((char*)d_ws + (size_t)M_ROWS * K_DIM * sizeof(bf16));

  conv_bf16<<<2048, 256, 0, stream>>>(x, Xb, (M_ROWS * K_DIM) / 4);
  build_gt<<<4096, 256, 0, stream>>>(core0, core1, GT);
  gemm_xg<<<MT2 * NT2, 256, 0, stream>>>(Xb, GT, bias, out);
}

// Round 10
// 336.083 us; speedup vs baseline: 1.0138x; 1.0138x over previous
//
#include <hip/hip_runtime.h>
#include <hip/hip_bf16.h>
#include <stdint.h>
#include <stddef.h>

using bf16 = __hip_bfloat16;

typedef __attribute__((ext_vector_type(4))) float f32x4;
typedef __attribute__((ext_vector_type(16))) float f32x16;
typedef __attribute__((ext_vector_type(8))) short bf16x8;
typedef __attribute__((ext_vector_type(4))) unsigned short u16x4;

#define K_DIM 4096
#define M_ROWS 8192
#define BM 256
#define BN 256
#define BK 64
#define NT (K_DIM / BK)      // 64 K-tiles
#define MT2 (M_ROWS / BM)    // 32
#define NT2 (K_DIM / BN)     // 16

template<bool B> struct BC { static constexpr bool value = B; };

// ---------------------------------------------------------------------------
// Kernel 1: f32 -> bf16 conversion (vectorized, grid-stride)
// ---------------------------------------------------------------------------
__global__ void conv_bf16(const float* __restrict__ in, bf16* __restrict__ outb, int n4) {
  int idx = blockIdx.x * blockDim.x + threadIdx.x;
  int stride = gridDim.x * blockDim.x;
  for (int k = idx; k < n4; k += stride) {
    f32x4 v = ((const f32x4*)in)[k];
    bf16 tmp[4];
    tmp[0] = __float2bfloat16(v.x);
    tmp[1] = __float2bfloat16(v.y);
    tmp[2] = __float2bfloat16(v.z);
    tmp[3] = __float2bfloat16(v.w);
    ((u16x4*)outb)[k] = *(const u16x4*)tmp;
  }
}

// ---------------------------------------------------------------------------
// Kernel 2: build G^T in bf16 (verified round 1).
// ---------------------------------------------------------------------------
__global__ void build_gt(const float* __restrict__ core0, const float* __restrict__ core1,
                         bf16* __restrict__ GT) {
  int j = blockIdx.x >> 6;
  int i = blockIdx.x & 63;
  __shared__ float c0s[64][16];
  __shared__ float c1s[64][16];
  int t = threadIdx.x;
#pragma unroll
  for (int rep = 0; rep < 4; ++rep) {
    int idx = rep * 256 + t;
    int row = idx >> 4;
    int b = idx & 15;
    size_t base = ((size_t)(j * 64 + row) * 64 + i) * 16 + b;
    c1s[row][b] = core1[base];
    c0s[row][b] = core0[base];
  }
  __syncthreads();
  int x = t & 63;
  int ys = t >> 6;
  float r1[16];
#pragma unroll
  for (int b = 0; b < 16; ++b) r1[b] = c1s[x][b];
#pragma unroll
  for (int yy = 0; yy < 16; ++yy) {
    int y = ys * 16 + yy;
    float acc = 0.f;
#pragma unroll
    for (int b = 0; b < 16; ++b) acc += r1[b] * c0s[y][b];
    GT[((size_t)(y * 64 + i) << 12) + (size_t)(j * 64 + x)] = __float2bfloat16(acc);
  }
}

// ---------------------------------------------------------------------------
// Kernel 3: 256x256 / BK=64 / 8-wave / mfma_32x32x16. K-step-split phases:
// phase p = {6 ds_read_b128 for ks=p+1 (ping-pong set) ; stage ; barrier ;
// lgkmcnt(6) (drains only the CONSUMED set; issued set drains UNDER MFMA) ;
// 8 independent MFMAs ks=p ; barrier}. Stages 1 tile ahead (pure dbuf);
// vmcnt(0) at ph3 is >= 2 phases after issue (no stall); cross-tile read
// placed AFTER vmcnt->barrier (race-closed).
// ---------------------------------------------------------------------------
__device__ __forceinline__ void gload_lds16(const bf16* g, bf16* l) {
  __builtin_amdgcn_global_load_lds(
      (const __attribute__((address_space(1))) unsigned int*)(g),
      (__attribute__((address_space(3))) unsigned int*)(l),
      16, 0, 0);
}

#define BARRIER() asm volatile("s_barrier" ::: "memory")
#define LGKM6() do { \
    asm volatile("s_waitcnt lgkmcnt(6)" ::: "memory"); \
    __builtin_amdgcn_sched_barrier(0); \
  } while (0)
#define LGKM0() do { \
    asm volatile("s_waitcnt lgkmcnt(0)" ::: "memory"); \
    __builtin_amdgcn_sched_barrier(0); \
  } while (0)
#define SP1() __builtin_amdgcn_s_setprio(1)
#define SP0() __builtin_amdgcn_s_setprio(0)
#define VMCNT0() asm volatile("s_waitcnt vmcnt(0)" ::: "memory")

__global__ __launch_bounds__(512, 2)
void gemm_xg(const bf16* __restrict__ Xb, const bf16* __restrict__ GT,
             const float* __restrict__ bias, float* __restrict__ out) {
  __shared__ bf16 As[2][BM * BK];   // 2 x 32 KiB
  __shared__ bf16 Bs[2][BN * BK];   // 2 x 32 KiB

  // XCD-aware swizzle: nwg = 512, divisible by 8
  int bid = blockIdx.x;
  int sb = (bid & 7) * (MT2 * NT2 / 8) + (bid >> 3);
  int bm = sb >> 4;
  int bn = sb & 15;

  int t = threadIdx.x;
  int lane = t & 63;
  int wid = t >> 6;

  // ---- staging addressing (linear LDS dest, inverse-swizzled global src) ----
  int srow = t >> 3;                    // 0..63
  int scol = t & 7;                     // dest 16B slot (linear)
  int sxor = scol ^ (srow & 7);         // pre-swizzled global slot
  const bf16* gA0 = Xb + ((size_t)(bm * BM + srow) * K_DIM) + sxor * 8;
  const bf16* gB0 = GT + ((size_t)(bn * BN + srow) * K_DIM) + sxor * 8;
  int lbase = srow * BK + scol * 8;

  auto sA = [&](int buf, int h, int kt) {
    const bf16* g = gA0 + (size_t)(h * 128) * K_DIM + (size_t)kt * BK;
    bf16* l = &As[buf][h * 128 * BK + lbase];
    gload_lds16(g, l);
    gload_lds16(g + (size_t)64 * K_DIM, l + 64 * BK);
  };
  auto sB = [&](int buf, int h, int kt) {
    const bf16* g = gB0 + (size_t)(h * 128) * K_DIM + (size_t)kt * BK;
    bf16* l = &Bs[buf][h * 128 * BK + lbase];
    gload_lds16(g, l);
    gload_lds16(g + (size_t)64 * K_DIM, l + 64 * BK);
  };

  // ---- fragment addressing (32x32x16: row = lane&31, k-run = (lane>>5)*8) ----
  int wm = wid >> 2;        // 0..1
  int wn = wid & 3;         // 0..3
  int l31 = lane & 31;
  int lh = lane >> 5;       // 0..1
  int x7 = l31 & 7;
  int abase = (wm * 128 + l31) * BK;   // + mi*32*64
  int bbase = (wn * 64 + l31) * BK;    // + ni*32*64

  f32x16 acc[4][2] = {};
  bf16x8 a0[4], b0[2], a1[4], b1[2];   // ping-pong fragment sets

  auto readset = [&](bf16x8 (&av)[4], bf16x8 (&bv)[2],
                     const bf16* Ab, const bf16* Bb, int ks) {
    int sofs = ((2 * ks + lh) ^ x7) << 3;
#pragma unroll
    for (int mi = 0; mi < 4; ++mi)
      av[mi] = *(const bf16x8*)&Ab[abase + mi * 2048 + sofs];
#pragma unroll
    for (int ni = 0; ni < 2; ++ni)
      bv[ni] = *(const bf16x8*)&Bb[bbase + ni * 2048 + sofs];
  };
  auto mfma8 = [&](bf16x8 (&av)[4], bf16x8 (&bv)[2]) {
    SP1();
#pragma unroll
    for (int mi = 0; mi < 4; ++mi)
#pragma unroll
      for (int ni = 0; ni < 2; ++ni)
        acc[mi][ni] = __builtin_amdgcn_mfma_f32_32x32x16_bf16(
            av[mi], bv[ni], acc[mi][ni], 0, 0, 0);
    SP0();
  };

  const bf16* A0 = &As[0][0];
  const bf16* B0 = &Bs[0][0];
  const bf16* A1 = &As[1][0];
  const bf16* B1 = &Bs[1][0];

  // ---- per-tile: 4 k-step phases ----
  auto tile = [&](int kt, const bf16* Ac, const bf16* Bc,
                  const bf16* An, const bf16* Bn, int nb, auto lastc) {
    constexpr bool LAST = decltype(lastc)::value;

    // ph0: MFMA ks0 (set0) ; read ks1 -> set1 ; stage A(t+1)
    if (!LAST) { sA(nb, 0, kt + 1); sA(nb, 1, kt + 1); }
    readset(a1, b1, Ac, Bc, 1);
    BARRIER(); LGKM6();
    mfma8(a0, b0);
    BARRIER();

    // ph1: MFMA ks1 (set1) ; read ks2 -> set0 ; stage B(t+1)
    if (!LAST) { sB(nb, 0, kt + 1); sB(nb, 1, kt + 1); }
    readset(a0, b0, Ac, Bc, 2);
    BARRIER(); LGKM6();
    mfma8(a1, b1);
    BARRIER();

    // ph2: MFMA ks2 (set0) ; read ks3 -> set1
    readset(a1, b1, Ac, Bc, 3);
    BARRIER(); LGKM6();
    mfma8(a0, b0);
    BARRIER();

    // ph3: MFMA ks3 (set1) ; vmcnt(0)+barrier then read ks0(t+1) -> set0
    if (!LAST) {
      VMCNT0();                 // own stage loads issued >=2 phases ago: no stall
      BARRIER();                // all waves' stages for t+1 now visible
      readset(a0, b0, An, Bn, 0);
      LGKM6();
      mfma8(a1, b1);
      BARRIER();
    } else {
      BARRIER(); LGKM0();
      mfma8(a1, b1);
    }
  };

  // ---- prologue: stage tile0; drain; pre-read ks0 into set0 ----
  sA(0, 0, 0); sA(0, 1, 0);
  sB(0, 0, 0); sB(0, 1, 0);
  VMCNT0();
  BARRIER();
  readset(a0, b0, A0, B0, 0);

#pragma unroll 1
  for (int i = 0; i < NT / 2 - 1; ++i) {
    tile(2 * i,     A0, B0, A1, B1, 1, BC<false>{});
    tile(2 * i + 1, A1, B1, A0, B0, 0, BC<false>{});
  }
  tile(NT - 2, A0, B0, A1, B1, 1, BC<false>{});
  tile(NT - 1, A1, B1, A0, B0, 0, BC<true>{});

  // ---- epilogue: 32x32 C/D layout: col=lane&31, row=(r&3)+8*(r>>2)+4*lh ----
  int colbase = bn * BN + wn * 64 + l31;
  int rowbase = bm * BM + wm * 128 + 4 * lh;
#pragma unroll
  for (int ni = 0; ni < 2; ++ni) {
    int col = colbase + ni * 32;
    float bv = bias[col];
#pragma unroll
    for (int mi = 0; mi < 4; ++mi) {
#pragma unroll
      for (int r = 0; r < 16; ++r) {
        int row = rowbase + mi * 32 + (r & 3) + 8 * (r >> 2);
        out[(size_t)row * K_DIM + col] = acc[mi][ni][r] + bv;
      }
    }
  }
}

// ---------------------------------------------------------------------------
extern "C" void kernel_launch(void* const* d_in, const int* in_sizes, int n_in,
                              void* d_out, int out_size, void* d_ws, size_t ws_size,
                              hipStream_t stream) {
  const float* x     = (const float*)d_in[0];
  const float* core0 = (const float*)d_in[1];
  const float* core1 = (const float*)d_in[2];
  const float* bias  = (const float*)d_in[3];
  float* out = (float*)d_out;

  bf16* Xb = (bf16*)d_ws;
  bf16* GT = (bf16*)((char*)d_ws + (size_t)M_ROWS * K_DIM * sizeof(bf16));

  conv_bf16<<<2048, 256, 0, stream>>>(x, Xb, (M_ROWS * K_DIM) / 4);
  build_gt<<<4096, 256, 0, stream>>>(core0, core1, GT);
  gemm_xg<<<MT2 * NT2, 512, 0, stream>>>(Xb, GT, bias, out);
}